// Round 15
// baseline (465.269 us; speedup 1.0000x reference)
//
#include <hip/hip_runtime.h>
#include <hip/hip_bf16.h>

#define CDIV(a,b) (((a)+(b)-1)/(b))

typedef __attribute__((ext_vector_type(8))) short short8_t;
typedef __attribute__((ext_vector_type(4))) float f32x4;

__device__ __forceinline__ float b2f(ushort u){
    union { uint i; float f; } v; v.i = ((uint)u) << 16; return v.f;
}
__device__ __forceinline__ ushort f2b(float f){
    __hip_bfloat16 h = __float2bfloat16(f);
    return *reinterpret_cast<ushort*>(&h);
}

// ---------------------------------------------------------------- bucketed CSR build
__global__ __launch_bounds__(256) void k_bcount(
    const int* __restrict__ dst, int E, int nbuck, int* __restrict__ bcnt)
{
    __shared__ int cnt[512];
    const int t = threadIdx.x;
    for (int i = t; i < nbuck; i += 256) cnt[i] = 0;
    __syncthreads();
    const int e0 = blockIdx.x * 4096;
    if (e0 + 4096 <= E){
        #pragma unroll
        for (int q = 0; q < 4; ++q){
            int4 d = *reinterpret_cast<const int4*>(dst + e0 + (q*256 + t)*4);
            atomicAdd(&cnt[d.x >> 8], 1);
            atomicAdd(&cnt[d.y >> 8], 1);
            atomicAdd(&cnt[d.z >> 8], 1);
            atomicAdd(&cnt[d.w >> 8], 1);
        }
    } else {
        #pragma unroll
        for (int q = 0; q < 16; ++q){
            int idx = e0 + q*256 + t;
            if (idx < E) atomicAdd(&cnt[dst[idx] >> 8], 1);
        }
    }
    __syncthreads();
    for (int i = t; i < nbuck; i += 256){
        int c = cnt[i];
        if (c) atomicAdd(&bcnt[i], c);
    }
}

__global__ void k_bscan(const int* __restrict__ bcnt, int nbuck, int E,
                        int* __restrict__ bbase, int* __restrict__ gcur)
{
    __shared__ int s[512];
    int t = threadIdx.x;
    int v = (t < nbuck) ? bcnt[t] : 0;
    s[t] = v;
    __syncthreads();
    for (int off = 1; off < 512; off <<= 1){
        int x = (t >= off) ? s[t-off] : 0;
        __syncthreads();
        s[t] += x;
        __syncthreads();
    }
    if (t < nbuck){ int e = s[t] - v; bbase[t] = e; gcur[t] = e; }
    if (t == 0) bbase[nbuck] = E;
}

__global__ __launch_bounds__(256) void k_bucketA(
    const int* __restrict__ src, const int* __restrict__ dst, int E,
    int nbuck, int* __restrict__ gcur, uint* __restrict__ ebuf)
{
    __shared__ int cnt[512];
    __shared__ int base[512];
    const int t  = threadIdx.x;
    const int e0 = blockIdx.x * 4096;
    for (int i = t; i < nbuck; i += 256) cnt[i] = 0;
    __syncthreads();
    uint pk[16]; int mb[16];
    #pragma unroll
    for (int q = 0; q < 16; ++q){
        int idx = e0 + q*256 + t;
        int b = -1; uint pkv = 0;
        if (idx < E){
            int s = src[idx], d = dst[idx];
            b = d >> 8;
            pkv = (uint)s | ((uint)(d & 255) << 24);
            atomicAdd(&cnt[b], 1);
        }
        mb[q] = b; pk[q] = pkv;
    }
    __syncthreads();
    for (int i = t; i < nbuck; i += 256){
        int c = cnt[i];
        base[i] = c ? atomicAdd(&gcur[i], c) : 0;
    }
    __syncthreads();
    for (int i = t; i < nbuck; i += 256) cnt[i] = 0;
    __syncthreads();
    #pragma unroll
    for (int q = 0; q < 16; ++q){
        if (mb[q] >= 0){
            int b   = mb[q];
            int pos = base[b] + atomicAdd(&cnt[b], 1);
            ebuf[pos] = pk[q];
        }
    }
}

__global__ __launch_bounds__(256) void k_build(
    const uint* __restrict__ ebuf, const int* __restrict__ bbase,
    int N, int E, int* __restrict__ row_ptr, float* __restrict__ inv_deg,
    int* __restrict__ col_idx)
{
    __shared__ int cnt[256];
    __shared__ int scn[256];
    const int b = blockIdx.x;
    const int t = threadIdx.x;
    const int n0 = b << 8;
    const int ebase = bbase[b], eend = bbase[b+1];

    cnt[t] = 0;
    __syncthreads();
    for (int j = ebase + t; j < eend; j += 256)
        atomicAdd(&cnt[ebuf[j] >> 24], 1);
    __syncthreads();

    int d = cnt[t];
    scn[t] = d;
    __syncthreads();
    for (int off = 1; off < 256; off <<= 1){
        int x = (t >= off) ? scn[t-off] : 0;
        __syncthreads();
        scn[t] += x;
        __syncthreads();
    }
    int excl = scn[t] - d;
    int node = n0 + t;
    if (node < N){
        row_ptr[node] = ebase + excl;
        inv_deg[node] = 1.0f / (float)(d > 1 ? d : 1);
    }
    if (b == 0 && t == 0) row_ptr[N] = E;

    cnt[t] = excl;
    __syncthreads();
    for (int j = ebase + t; j < eend; j += 256){
        uint e = ebuf[j];
        int p = atomicAdd(&cnt[e >> 24], 1);
        col_idx[ebase + p] = (int)(e & 0xFFFFFFu);
    }
}

// ---------------------------------------------------------------- conversions
__global__ void k_cvt_x(const float* __restrict__ in, ushort* __restrict__ out, int n4){
    int i = blockIdx.x*blockDim.x + threadIdx.x;
    if (i >= n4) return;
    float4 v = reinterpret_cast<const float4*>(in)[i];
    ushort4 o; o.x=f2b(v.x); o.y=f2b(v.y); o.z=f2b(v.z); o.w=f2b(v.w);
    reinterpret_cast<ushort4*>(out)[i] = o;
}

__global__ void k_cvt_w(const float* __restrict__ Wl, const float* __restrict__ Wr,
                        const float* __restrict__ W1, const float* __restrict__ W2,
                        ushort* __restrict__ WtL, ushort* __restrict__ WtR,
                        ushort* __restrict__ Wt1, ushort* __restrict__ Wt2)
{
    int i = blockIdx.x*blockDim.x + threadIdx.x;
    const int S = 16384;
    if (i < 3*S){
        int s = i / S, r = i - s*S;
        int k = r >> 7, c = r & 127;
        WtL[s*S + c*128 + k] = f2b(Wl[i]);
    } else if (i < 6*S){
        i -= 3*S;
        int s = i / S, r = i - s*S;
        int k = r >> 7, c = r & 127;
        WtR[s*S + c*128 + k] = f2b(Wr[i]);
    } else if (i < 10*S){
        i -= 6*S;
        int s = i / S, r = i - s*S;
        int k = r >> 7, c = r & 127;
        Wt1[s*S + c*128 + k] = f2b(W1[i]);
    } else {
        i -= 10*S;
        if (i < 8192){
            int k = i >> 6, c = i & 63;
            Wt2[c*128 + k] = f2b(W2[i]);
        }
    }
}

// ---------------------------------------------------------------- aggregation (bf16, row-major)
template<int NORM>
__global__ __launch_bounds__(256) void k_agg_bf(
    const ushort* __restrict__ h, const int* __restrict__ row_ptr,
    const int* __restrict__ col_idx, const float* __restrict__ inv_deg,
    const float* __restrict__ ssp, ushort* __restrict__ agg, int N)
{
    int node = (blockIdx.x*blockDim.x + threadIdx.x) >> 6;
    int lane = threadIdx.x & 63;
    if (node >= N) return;
    const int g = lane >> 4, l15 = lane & 15;
    const int beg = row_ptr[node], end = row_ptr[node+1];
    const size_t co = (size_t)l15 * 8;

    float scv[8], shv[8];
    if (NORM){
        float4 c0 = *reinterpret_cast<const float4*>(ssp + co);
        float4 c1 = *reinterpret_cast<const float4*>(ssp + co + 4);
        float4 s0 = *reinterpret_cast<const float4*>(ssp + 128 + co);
        float4 s1 = *reinterpret_cast<const float4*>(ssp + 128 + co + 4);
        scv[0]=c0.x; scv[1]=c0.y; scv[2]=c0.z; scv[3]=c0.w;
        scv[4]=c1.x; scv[5]=c1.y; scv[6]=c1.z; scv[7]=c1.w;
        shv[0]=s0.x; shv[1]=s0.y; shv[2]=s0.z; shv[3]=s0.w;
        shv[4]=s1.x; shv[5]=s1.y; shv[6]=s1.z; shv[7]=s1.w;
    }

    float2 a2[4];
    #pragma unroll
    for (int q = 0; q < 4; ++q) a2[q] = make_float2(0.f, 0.f);

    auto acc8 = [&](uint4 v){
        uint w[4] = {v.x, v.y, v.z, v.w};
        #pragma unroll
        for (int q = 0; q < 4; ++q){
            union { uint i; float f; } lo, hi;
            lo.i = w[q] << 16;
            hi.i = w[q] & 0xffff0000u;
            float fl = lo.f, fh = hi.f;
            if (NORM){
                fl = fmaxf(fl*scv[2*q]   + shv[2*q],   0.f);
                fh = fmaxf(fh*scv[2*q+1] + shv[2*q+1], 0.f);
            }
            a2[q].x += fl;
            a2[q].y += fh;
        }
    };

    int j = beg + g;
    while (j + 4 < end){
        int s0 = col_idx[j];
        int s1 = col_idx[j+4];
        uint4 v0 = *reinterpret_cast<const uint4*>(h + (size_t)s0*128 + co);
        uint4 v1 = *reinterpret_cast<const uint4*>(h + (size_t)s1*128 + co);
        acc8(v0); acc8(v1);
        j += 8;
    }
    if (j < end){
        int s0 = col_idx[j];
        uint4 v0 = *reinterpret_cast<const uint4*>(h + (size_t)s0*128 + co);
        acc8(v0);
    }

    #pragma unroll
    for (int q = 0; q < 4; ++q){
        a2[q].x += __shfl_xor(a2[q].x, 16);
        a2[q].y += __shfl_xor(a2[q].y, 16);
        a2[q].x += __shfl_xor(a2[q].x, 32);
        a2[q].y += __shfl_xor(a2[q].y, 32);
    }

    if (g == 0){
        float sc = inv_deg[node];
        uint r[4];
        #pragma unroll
        for (int q = 0; q < 4; ++q)
            r[q] = (uint)f2b(a2[q].x*sc) | ((uint)f2b(a2[q].y*sc) << 16);
        *reinterpret_cast<uint4*>(agg + (size_t)node*128 + co) =
            make_uint4(r[0], r[1], r[2], r[3]);
    }
}

// ---------------------------------------------------------------- MFMA GEMM
// A-loads hoisted ahead of B-stage + barrier (software pipeline).
__device__ __forceinline__ short8_t norm_frag(short8_t a, const float* __restrict__ sp,
                                              int kbase, int leaky)
{
    float4 c0 = *reinterpret_cast<const float4*>(sp + kbase);
    float4 c1 = *reinterpret_cast<const float4*>(sp + kbase + 4);
    float4 h0 = *reinterpret_cast<const float4*>(sp + 128 + kbase);
    float4 h1 = *reinterpret_cast<const float4*>(sp + 128 + kbase + 4);
    float cs[8] = {c0.x,c0.y,c0.z,c0.w,c1.x,c1.y,c1.z,c1.w};
    float hs[8] = {h0.x,h0.y,h0.z,h0.w,h1.x,h1.y,h1.z,h1.w};
    uint* au = reinterpret_cast<uint*>(&a);
    short8_t r;
    uint* ru = reinterpret_cast<uint*>(&r);
    #pragma unroll
    for (int q = 0; q < 4; ++q){
        float lo = b2f((ushort)(au[q] & 0xffffu));
        float hi = b2f((ushort)(au[q] >> 16));
        lo = lo*cs[2*q]   + hs[2*q];
        hi = hi*cs[2*q+1] + hs[2*q+1];
        if (leaky){ lo = lo > 0.f ? lo : 0.01f*lo; hi = hi > 0.f ? hi : 0.01f*hi; }
        else      { lo = fmaxf(lo, 0.f); hi = fmaxf(hi, 0.f); }
        ru[q] = (uint)f2b(lo) | ((uint)f2b(hi) << 16);
    }
    return r;
}

template<int NCF, int STATS, int OUTBF>
__global__ __launch_bounds__(256) void k_gemm_mfma(
    const ushort* __restrict__ A0, const ushort* __restrict__ T0,
    const ushort* __restrict__ A1, const ushort* __restrict__ T1,
    const ushort* __restrict__ A2, const ushort* __restrict__ T2,
    const ushort* __restrict__ A3, const ushort* __restrict__ T3,
    const float* __restrict__ ns0, const float* __restrict__ ns1,
    const float* __restrict__ ns2, const float* __restrict__ ns3,
    int m0, int m1, int m2, int m3,
    int P, const float* __restrict__ bias,
    ushort* __restrict__ out_bf, float* __restrict__ out_f32,
    float* __restrict__ partials, int N)
{
    __shared__ ushort Ws[17920];   // 35840 B
    const int t   = threadIdx.x;
    const int w   = t >> 6, l = t & 63;
    const int l15 = l & 15, lg = l >> 4;
    const int r0   = blockIdx.x * 128;
    const int wrow = w * 32;

    f32x4 acc[2][NCF];
    #pragma unroll
    for (int i = 0; i < 2; ++i)
        #pragma unroll
        for (int j = 0; j < NCF; ++j) acc[i][j] = (f32x4){0.f,0.f,0.f,0.f};

    for (int p = 0; p < P; ++p){
        const ushort* A  = (p==0)?A0:(p==1)?A1:(p==2)?A2:A3;
        const ushort* T  = (p==0)?T0:(p==1)?T1:(p==2)?T2:T3;
        const float*  ns = (p==0)?ns0:(p==1)?ns1:(p==2)?ns2:ns3;
        const int     md = (p==0)?m0:(p==1)?m1:(p==2)?m2:m3;
        if (p) __syncthreads();

        // ---- issue all 8 A-fragment loads first (latency hides under staging+barrier)
        short8_t a[4][2];
        #pragma unroll
        for (int kk = 0; kk < 4; ++kk){
            #pragma unroll
            for (int rf = 0; rf < 2; ++rf){
                size_t gr = (size_t)(r0 + wrow + rf*16 + l15);
                a[kk][rf] = *reinterpret_cast<const short8_t*>(A + gr*128 + kk*32 + lg*8);
            }
        }

        // ---- stage B into LDS (XOR-swizzled)
        #pragma unroll
        for (int q = 0; q < NCF; ++q){
            int lin  = q*256 + t;
            int row  = lin >> 4, c16 = lin & 15;
            int c16s = c16 ^ (row & 7);
            uint4 v = *reinterpret_cast<const uint4*>(T + (size_t)row*128 + c16*8);
            *reinterpret_cast<uint4*>(&Ws[row*128 + c16s*8]) = v;
        }
        __syncthreads();

        if (md){
            #pragma unroll
            for (int kk = 0; kk < 4; ++kk){
                a[kk][0] = norm_frag(a[kk][0], ns, kk*32 + lg*8, md == 2);
                a[kk][1] = norm_frag(a[kk][1], ns, kk*32 + lg*8, md == 2);
            }
        }

        #pragma unroll
        for (int kk = 0; kk < 4; ++kk){
            const int k0 = kk*32;
            #pragma unroll
            for (int cf = 0; cf < NCF; ++cf){
                int row  = cf*16 + l15;
                int c16  = (k0 >> 3) + lg;
                int c16s = c16 ^ (row & 7);
                short8_t b = *reinterpret_cast<const short8_t*>(&Ws[row*128 + c16s*8]);
                acc[0][cf] = __builtin_amdgcn_mfma_f32_16x16x32_bf16(a[kk][0], b, acc[0][cf], 0, 0, 0);
                acc[1][cf] = __builtin_amdgcn_mfma_f32_16x16x32_bf16(a[kk][1], b, acc[1][cf], 0, 0, 0);
            }
        }
    }

    float bs[NCF];
    #pragma unroll
    for (int cf = 0; cf < NCF; ++cf) bs[cf] = bias[cf*16 + l15];

    float s1[NCF], s2[NCF];
    #pragma unroll
    for (int cf = 0; cf < NCF; ++cf){ s1[cf] = 0.f; s2[cf] = 0.f; }

    __syncthreads();   // Ws B-staging done; reuse as C tile

    #pragma unroll
    for (int rf = 0; rf < 2; ++rf){
        #pragma unroll
        for (int q = 0; q < 4; ++q){
            int row_l = wrow + rf*16 + lg*4 + q;
            bool valid = (r0 + row_l) < N;
            #pragma unroll
            for (int cf = 0; cf < NCF; ++cf){
                float v = acc[rf][cf][q] + bs[cf];
                if (STATS && valid){ s1[cf] += v; s2[cf] += v*v; }
                if (OUTBF) Ws[row_l*140 + cf*16 + l15] = f2b(v);
                else       reinterpret_cast<float*>(Ws)[row_l*70 + cf*16 + l15] = v;
            }
        }
    }
    __syncthreads();

    const int tr = t >> 4, tc = t & 15;
    #pragma unroll
    for (int i = 0; i < 8; ++i){
        int row_l = i*16 + tr;
        int gr = r0 + row_l;
        if (gr < N){
            if (OUTBF){
                uint4 v = *reinterpret_cast<const uint4*>(&Ws[row_l*140 + tc*8]);
                *reinterpret_cast<uint4*>(&out_bf[(size_t)gr*(NCF*16) + tc*8]) = v;
            } else {
                float4 v = *reinterpret_cast<const float4*>(
                    &reinterpret_cast<float*>(Ws)[row_l*70 + tc*4]);
                *reinterpret_cast<float4*>(&out_f32[(size_t)gr*(NCF*16) + tc*4]) = v;
            }
        }
    }

    if (STATS){
        #pragma unroll
        for (int cf = 0; cf < NCF; ++cf){
            s1[cf] += __shfl_xor(s1[cf], 16);
            s1[cf] += __shfl_xor(s1[cf], 32);
            s2[cf] += __shfl_xor(s2[cf], 16);
            s2[cf] += __shfl_xor(s2[cf], 32);
        }
        if (l < 16){
            float* pb = partials + (size_t)(blockIdx.x*4 + w)*256;
            #pragma unroll
            for (int cf = 0; cf < NCF; ++cf){
                pb[cf*16 + l15]       = s1[cf];
                pb[128 + cf*16 + l15] = s2[cf];
            }
        }
    }
}

// ---------------------------------------------------------------- BN reduce (256 thr)
__global__ __launch_bounds__(256) void k_bnreduce(
    const float* __restrict__ partials, int I, int N,
    const float* __restrict__ gamma, const float* __restrict__ beta,
    float* __restrict__ ss)
{
    __shared__ float red[512];
    int c = blockIdx.x;
    int t = threadIdx.x;
    float s1 = 0.f, s2 = 0.f;
    for (int i = t; i < I; i += 256){
        s1 += partials[(size_t)i*256 + c];
        s2 += partials[(size_t)i*256 + 128 + c];
    }
    red[t] = s1; red[256+t] = s2;
    __syncthreads();
    for (int off = 128; off; off >>= 1){
        if (t < off){ red[t] += red[t+off]; red[256+t] += red[256+t+off]; }
        __syncthreads();
    }
    if (t == 0){
        float m   = red[0] / (float)N;
        float var = red[256] / (float)N - m*m;
        float sc  = rsqrtf(var + 1e-5f) * gamma[c];
        ss[c]     = sc;
        ss[128+c] = beta[c] - m*sc;
    }
}

// ---------------------------------------------------------------- launch
extern "C" void kernel_launch(void* const* d_in, const int* in_sizes, int n_in,
                              void* d_out, int out_size, void* d_ws, size_t ws_size,
                              hipStream_t stream)
{
    const float* x     = (const float*)d_in[0];
    const int*   ei    = (const int*)  d_in[1];
    const float* Wl    = (const float*)d_in[2];
    const float* bl    = (const float*)d_in[3];
    const float* Wr    = (const float*)d_in[4];
    const float* gamma = (const float*)d_in[5];
    const float* beta  = (const float*)d_in[6];
    const float* W1    = (const float*)d_in[7];
    const float* b1    = (const float*)d_in[8];
    const float* g1    = (const float*)d_in[9];
    const float* be1   = (const float*)d_in[10];
    const float* W2    = (const float*)d_in[11];
    const float* b2    = (const float*)d_in[12];
    float* out = (float*)d_out;

    const int N  = in_sizes[0] / 128;
    const int E  = in_sizes[1] / 2;
    const int NB = CDIV(N, 128);
    const size_t NPAD = (size_t)NB * 128;
    const int* src = ei;
    const int* dst = ei + E;

    const int NBUCK = CDIV(N, 256);

    char* w = (char*)d_ws;
    const size_t SB = NPAD * 128 * sizeof(ushort);
    ushort* x_bf = (ushort*)(w + 0*SB);
    ushort* pre0 = (ushort*)(w + 1*SB);
    ushort* pre1 = (ushort*)(w + 2*SB);
    ushort* pre2 = (ushort*)(w + 3*SB);
    ushort* aggb = (ushort*)(w + 4*SB);
    ushort* preh = (ushort*)(w + 5*SB);
    char* p = w + 6*SB;
    ushort* WtL = (ushort*)p;  p += (size_t)3*16384*2;
    ushort* WtR = (ushort*)p;  p += (size_t)3*16384*2;
    ushort* Wt1 = (ushort*)p;  p += (size_t)4*16384*2;
    ushort* Wt2 = (ushort*)p;  p += (size_t)8192*2;
    float* partials = (float*)p; p += (size_t)NB*4*256*sizeof(float);
    uint*  ebuf     = (uint*)p;  p += (size_t)E*4;
    int*   col_idx  = (int*)p;   p += (size_t)E*4;
    int*   row_ptr  = (int*)p;   p += (size_t)(N+1)*4;
    float* inv_deg  = (float*)p; p += (size_t)N*4;
    int*   bcnt     = (int*)p;   p += 512*4;
    int*   bbase    = (int*)p;   p += 516*4;
    int*   gcur     = (int*)p;   p += 512*4;
    float* ss0      = (float*)p; p += 256*4;
    float* ss1      = (float*)p; p += 256*4;
    float* ss2      = (float*)p; p += 256*4;
    float* ssh      = (float*)p; p += 256*4;

    // conversions
    const int n4 = N * 32;
    k_cvt_x<<<CDIV(n4,256), 256, 0, stream>>>(x, x_bf, n4);
    k_cvt_w<<<CDIV(10*16384+8192,256), 256, 0, stream>>>(Wl, Wr, W1, W2, WtL, WtR, Wt1, Wt2);

    // bucketed CSR build
    hipMemsetAsync(bcnt, 0, 512*4, stream);
    k_bcount<<<CDIV(E,4096), 256, 0, stream>>>(dst, E, NBUCK, bcnt);
    k_bscan<<<1, 512, 0, stream>>>(bcnt, NBUCK, E, bbase, gcur);
    k_bucketA<<<CDIV(E,4096), 256, 0, stream>>>(src, dst, E, NBUCK, gcur, ebuf);
    k_build<<<NBUCK, 256, 0, stream>>>(ebuf, bbase, N, E, row_ptr, inv_deg, col_idx);

    ushort* pre[3] = {pre0, pre1, pre2};
    float*  ssl[3] = {ss0, ss1, ss2};
    const int I = NB * 4;

    // ---- 3 SAGE layers (normalized h never materialized; norm at consumers)
    for (int L = 0; L < 3; ++L){
        if (L == 0)
            k_agg_bf<0><<<CDIV(N,4), 256, 0, stream>>>(x_bf, row_ptr, col_idx, inv_deg,
                                                       nullptr, aggb, N);
        else
            k_agg_bf<1><<<CDIV(N,4), 256, 0, stream>>>(pre[L-1], row_ptr, col_idx, inv_deg,
                                                       ssl[L-1], aggb, N);
        const ushort* hsrc = (L == 0) ? x_bf : pre[L-1];
        const float*  hns  = (L == 0) ? nullptr : ssl[L-1];
        int hmode = (L == 0) ? 0 : 1;
        k_gemm_mfma<8,1,1><<<NB, 256, 0, stream>>>(
            aggb, WtL + (size_t)L*16384,
            hsrc, WtR + (size_t)L*16384,
            nullptr, nullptr, nullptr, nullptr,
            nullptr, hns, nullptr, nullptr,
            0, hmode, 0, 0,
            2, bl + (size_t)L*128, pre[L], nullptr, partials, N);
        k_bnreduce<<<128, 256, 0, stream>>>(partials, I, N,
            gamma + (size_t)L*128, beta + (size_t)L*128, ssl[L]);
    }

    // ---- head: z = [x, h1, h2, h3] @ W1 + b1 (h applied from pre via ss)
    k_gemm_mfma<8,1,1><<<NB, 256, 0, stream>>>(
        x_bf, Wt1 + 0,
        pre0, Wt1 + 16384,
        pre1, Wt1 + 2*16384,
        pre2, Wt1 + 3*16384,
        nullptr, ss0, ss1, ss2,
        0, 1, 1, 1,
        4, b1, preh, nullptr, partials, N);
    k_bnreduce<<<128, 256, 0, stream>>>(partials, I, N, g1, be1, ssh);

    // ---- out: leaky(bn(preh)) @ W2 + b2 -> f32 d_out
    k_gemm_mfma<4,0,0><<<NB, 256, 0, stream>>>(
        preh, Wt2, nullptr, nullptr, nullptr, nullptr, nullptr, nullptr,
        ssh, nullptr, nullptr, nullptr,
        2, 0, 0, 0,
        1, b2, nullptr, out, partials, N);
}

// Round 16
// 446.145 us; speedup vs baseline: 1.0429x; 1.0429x over previous
//
#include <hip/hip_runtime.h>
#include <hip/hip_bf16.h>

#define CDIV(a,b) (((a)+(b)-1)/(b))

typedef __attribute__((ext_vector_type(8))) short short8_t;
typedef __attribute__((ext_vector_type(4))) float f32x4;

__device__ __forceinline__ float b2f(ushort u){
    union { uint i; float f; } v; v.i = ((uint)u) << 16; return v.f;
}
__device__ __forceinline__ ushort f2b(float f){
    __hip_bfloat16 h = __float2bfloat16(f);
    return *reinterpret_cast<ushort*>(&h);
}

// ---------------------------------------------------------------- bucketed CSR build
__global__ __launch_bounds__(256) void k_bcount(
    const int* __restrict__ dst, int E, int nbuck, int* __restrict__ bcnt)
{
    __shared__ int cnt[512];
    const int t = threadIdx.x;
    for (int i = t; i < nbuck; i += 256) cnt[i] = 0;
    __syncthreads();
    const int e0 = blockIdx.x * 4096;
    #pragma unroll
    for (int q = 0; q < 16; ++q){
        int idx = e0 + q*256 + t;
        if (idx < E) atomicAdd(&cnt[dst[idx] >> 8], 1);
    }
    __syncthreads();
    for (int i = t; i < nbuck; i += 256){
        int c = cnt[i];
        if (c) atomicAdd(&bcnt[i], c);
    }
}

__global__ void k_bscan(const int* __restrict__ bcnt, int nbuck, int E,
                        int* __restrict__ bbase, int* __restrict__ gcur)
{
    __shared__ int s[512];
    int t = threadIdx.x;
    int v = (t < nbuck) ? bcnt[t] : 0;
    s[t] = v;
    __syncthreads();
    for (int off = 1; off < 512; off <<= 1){
        int x = (t >= off) ? s[t-off] : 0;
        __syncthreads();
        s[t] += x;
        __syncthreads();
    }
    if (t < nbuck){ int e = s[t] - v; bbase[t] = e; gcur[t] = e; }
    if (t == 0) bbase[nbuck] = E;
}

__global__ __launch_bounds__(256) void k_bucketA(
    const int* __restrict__ src, const int* __restrict__ dst, int E,
    int nbuck, int* __restrict__ gcur, uint* __restrict__ ebuf)
{
    __shared__ int cnt[512];
    __shared__ int base[512];
    const int t  = threadIdx.x;
    const int e0 = blockIdx.x * 4096;
    for (int i = t; i < nbuck; i += 256) cnt[i] = 0;
    __syncthreads();
    uint pk[16]; int mb[16];
    #pragma unroll
    for (int q = 0; q < 16; ++q){
        int idx = e0 + q*256 + t;
        int b = -1; uint pkv = 0;
        if (idx < E){
            int s = src[idx], d = dst[idx];
            b = d >> 8;
            pkv = (uint)s | ((uint)(d & 255) << 24);
            atomicAdd(&cnt[b], 1);
        }
        mb[q] = b; pk[q] = pkv;
    }
    __syncthreads();
    for (int i = t; i < nbuck; i += 256){
        int c = cnt[i];
        base[i] = c ? atomicAdd(&gcur[i], c) : 0;
    }
    __syncthreads();
    for (int i = t; i < nbuck; i += 256) cnt[i] = 0;
    __syncthreads();
    #pragma unroll
    for (int q = 0; q < 16; ++q){
        if (mb[q] >= 0){
            int b   = mb[q];
            int pos = base[b] + atomicAdd(&cnt[b], 1);
            ebuf[pos] = pk[q];
        }
    }
}

__global__ __launch_bounds__(256) void k_build(
    const uint* __restrict__ ebuf, const int* __restrict__ bbase,
    int N, int E, int* __restrict__ row_ptr, float* __restrict__ inv_deg,
    int* __restrict__ col_idx)
{
    __shared__ int cnt[256];
    __shared__ int scn[256];
    const int b = blockIdx.x;
    const int t = threadIdx.x;
    const int n0 = b << 8;
    const int ebase = bbase[b], eend = bbase[b+1];

    cnt[t] = 0;
    __syncthreads();
    for (int j = ebase + t; j < eend; j += 256)
        atomicAdd(&cnt[ebuf[j] >> 24], 1);
    __syncthreads();

    int d = cnt[t];
    scn[t] = d;
    __syncthreads();
    for (int off = 1; off < 256; off <<= 1){
        int x = (t >= off) ? scn[t-off] : 0;
        __syncthreads();
        scn[t] += x;
        __syncthreads();
    }
    int excl = scn[t] - d;
    int node = n0 + t;
    if (node < N){
        row_ptr[node] = ebase + excl;
        inv_deg[node] = 1.0f / (float)(d > 1 ? d : 1);
    }
    if (b == 0 && t == 0) row_ptr[N] = E;

    cnt[t] = excl;
    __syncthreads();
    for (int j = ebase + t; j < eend; j += 256){
        uint e = ebuf[j];
        int p = atomicAdd(&cnt[e >> 24], 1);
        col_idx[ebase + p] = (int)(e & 0xFFFFFFu);
    }
}

// ---------------------------------------------------------------- conversions
__global__ void k_cvt_x(const float* __restrict__ in, ushort* __restrict__ out, int n4){
    int i = blockIdx.x*blockDim.x + threadIdx.x;
    if (i >= n4) return;
    float4 v = reinterpret_cast<const float4*>(in)[i];
    ushort4 o; o.x=f2b(v.x); o.y=f2b(v.y); o.z=f2b(v.z); o.w=f2b(v.w);
    reinterpret_cast<ushort4*>(out)[i] = o;
}

// merged weight transpose: Wl(3 slabs 128x128) | Wr(3) | W1(4) | W2(1 slab 128x64)
__global__ void k_cvt_w(const float* __restrict__ Wl, const float* __restrict__ Wr,
                        const float* __restrict__ W1, const float* __restrict__ W2,
                        ushort* __restrict__ WtL, ushort* __restrict__ WtR,
                        ushort* __restrict__ Wt1, ushort* __restrict__ Wt2)
{
    int i = blockIdx.x*blockDim.x + threadIdx.x;
    const int S = 16384;
    if (i < 3*S){
        int s = i / S, r = i - s*S;
        int k = r >> 7, c = r & 127;
        WtL[s*S + c*128 + k] = f2b(Wl[i]);
    } else if (i < 6*S){
        i -= 3*S;
        int s = i / S, r = i - s*S;
        int k = r >> 7, c = r & 127;
        WtR[s*S + c*128 + k] = f2b(Wr[i]);
    } else if (i < 10*S){
        i -= 6*S;
        int s = i / S, r = i - s*S;
        int k = r >> 7, c = r & 127;
        Wt1[s*S + c*128 + k] = f2b(W1[i]);
    } else {
        i -= 10*S;
        if (i < 8192){
            int k = i >> 6, c = i & 63;
            Wt2[c*128 + k] = f2b(W2[i]);
        }
    }
}

// ---------------------------------------------------------------- aggregation (bf16, row-major)
// wave = node; 4 groups x 16 lanes, dwordx4/lane, 2-deep pipeline.
// NORM=1: gathered values are pre-BN; apply relu(v*sc+sh) on the fly.
template<int NORM>
__global__ __launch_bounds__(256) void k_agg_bf(
    const ushort* __restrict__ h, const int* __restrict__ row_ptr,
    const int* __restrict__ col_idx, const float* __restrict__ inv_deg,
    const float* __restrict__ ssp, ushort* __restrict__ agg, int N)
{
    int node = (blockIdx.x*blockDim.x + threadIdx.x) >> 6;
    int lane = threadIdx.x & 63;
    if (node >= N) return;
    const int g = lane >> 4, l15 = lane & 15;
    const int beg = row_ptr[node], end = row_ptr[node+1];
    const size_t co = (size_t)l15 * 8;

    float scv[8], shv[8];
    if (NORM){
        float4 c0 = *reinterpret_cast<const float4*>(ssp + co);
        float4 c1 = *reinterpret_cast<const float4*>(ssp + co + 4);
        float4 s0 = *reinterpret_cast<const float4*>(ssp + 128 + co);
        float4 s1 = *reinterpret_cast<const float4*>(ssp + 128 + co + 4);
        scv[0]=c0.x; scv[1]=c0.y; scv[2]=c0.z; scv[3]=c0.w;
        scv[4]=c1.x; scv[5]=c1.y; scv[6]=c1.z; scv[7]=c1.w;
        shv[0]=s0.x; shv[1]=s0.y; shv[2]=s0.z; shv[3]=s0.w;
        shv[4]=s1.x; shv[5]=s1.y; shv[6]=s1.z; shv[7]=s1.w;
    }

    float2 a2[4];
    #pragma unroll
    for (int q = 0; q < 4; ++q) a2[q] = make_float2(0.f, 0.f);

    auto acc8 = [&](uint4 v){
        uint w[4] = {v.x, v.y, v.z, v.w};
        #pragma unroll
        for (int q = 0; q < 4; ++q){
            union { uint i; float f; } lo, hi;
            lo.i = w[q] << 16;
            hi.i = w[q] & 0xffff0000u;
            float fl = lo.f, fh = hi.f;
            if (NORM){
                fl = fmaxf(fl*scv[2*q]   + shv[2*q],   0.f);
                fh = fmaxf(fh*scv[2*q+1] + shv[2*q+1], 0.f);
            }
            a2[q].x += fl;
            a2[q].y += fh;
        }
    };

    int j = beg + g;
    while (j + 4 < end){
        int s0 = col_idx[j];
        int s1 = col_idx[j+4];
        uint4 v0 = *reinterpret_cast<const uint4*>(h + (size_t)s0*128 + co);
        uint4 v1 = *reinterpret_cast<const uint4*>(h + (size_t)s1*128 + co);
        acc8(v0); acc8(v1);
        j += 8;
    }
    if (j < end){
        int s0 = col_idx[j];
        uint4 v0 = *reinterpret_cast<const uint4*>(h + (size_t)s0*128 + co);
        acc8(v0);
    }

    #pragma unroll
    for (int q = 0; q < 4; ++q){
        a2[q].x += __shfl_xor(a2[q].x, 16);
        a2[q].y += __shfl_xor(a2[q].y, 16);
        a2[q].x += __shfl_xor(a2[q].x, 32);
        a2[q].y += __shfl_xor(a2[q].y, 32);
    }

    if (g == 0){
        float sc = inv_deg[node];
        uint r[4];
        #pragma unroll
        for (int q = 0; q < 4; ++q)
            r[q] = (uint)f2b(a2[q].x*sc) | ((uint)f2b(a2[q].y*sc) << 16);
        *reinterpret_cast<uint4*>(agg + (size_t)node*128 + co) =
            make_uint4(r[0], r[1], r[2], r[3]);
    }
}

// ---------------------------------------------------------------- MFMA GEMM (LDS-staged B, LDS-transpose epilogue)
// A-operand norm-at-load: mode 0=raw, 1=relu(bn), 2=leaky(bn)
__device__ __forceinline__ short8_t norm_frag(short8_t a, const float* __restrict__ sp,
                                              int kbase, int leaky)
{
    float4 c0 = *reinterpret_cast<const float4*>(sp + kbase);
    float4 c1 = *reinterpret_cast<const float4*>(sp + kbase + 4);
    float4 h0 = *reinterpret_cast<const float4*>(sp + 128 + kbase);
    float4 h1 = *reinterpret_cast<const float4*>(sp + 128 + kbase + 4);
    float cs[8] = {c0.x,c0.y,c0.z,c0.w,c1.x,c1.y,c1.z,c1.w};
    float hs[8] = {h0.x,h0.y,h0.z,h0.w,h1.x,h1.y,h1.z,h1.w};
    uint* au = reinterpret_cast<uint*>(&a);
    short8_t r;
    uint* ru = reinterpret_cast<uint*>(&r);
    #pragma unroll
    for (int q = 0; q < 4; ++q){
        float lo = b2f((ushort)(au[q] & 0xffffu));
        float hi = b2f((ushort)(au[q] >> 16));
        lo = lo*cs[2*q]   + hs[2*q];
        hi = hi*cs[2*q+1] + hs[2*q+1];
        if (leaky){ lo = lo > 0.f ? lo : 0.01f*lo; hi = hi > 0.f ? hi : 0.01f*hi; }
        else      { lo = fmaxf(lo, 0.f); hi = fmaxf(hi, 0.f); }
        ru[q] = (uint)f2b(lo) | ((uint)f2b(hi) << 16);
    }
    return r;
}

// LDS: union of B-staging (NCF*2048 ushorts) and C-transpose tile (128 rows x 140 ushorts / 70 floats)
template<int NCF, int STATS, int OUTBF>
__global__ __launch_bounds__(256) void k_gemm_mfma(
    const ushort* __restrict__ A0, const ushort* __restrict__ T0,
    const ushort* __restrict__ A1, const ushort* __restrict__ T1,
    const ushort* __restrict__ A2, const ushort* __restrict__ T2,
    const ushort* __restrict__ A3, const ushort* __restrict__ T3,
    const float* __restrict__ ns0, const float* __restrict__ ns1,
    const float* __restrict__ ns2, const float* __restrict__ ns3,
    int m0, int m1, int m2, int m3,
    int P, const float* __restrict__ bias,
    ushort* __restrict__ out_bf, float* __restrict__ out_f32,
    float* __restrict__ partials, int N)
{
    __shared__ ushort Ws[17920];   // 35840 B
    const int t   = threadIdx.x;
    const int w   = t >> 6, l = t & 63;
    const int l15 = l & 15, lg = l >> 4;
    const int r0   = blockIdx.x * 128;
    const int wrow = w * 32;

    f32x4 acc[2][NCF];
    #pragma unroll
    for (int i = 0; i < 2; ++i)
        #pragma unroll
        for (int j = 0; j < NCF; ++j) acc[i][j] = (f32x4){0.f,0.f,0.f,0.f};

    for (int p = 0; p < P; ++p){
        const ushort* A  = (p==0)?A0:(p==1)?A1:(p==2)?A2:A3;
        const ushort* T  = (p==0)?T0:(p==1)?T1:(p==2)?T2:T3;
        const float*  ns = (p==0)?ns0:(p==1)?ns1:(p==2)?ns2:ns3;
        const int     md = (p==0)?m0:(p==1)?m1:(p==2)?m2:m3;
        if (p) __syncthreads();
        #pragma unroll
        for (int q = 0; q < NCF; ++q){
            int lin  = q*256 + t;
            int row  = lin >> 4, c16 = lin & 15;
            int c16s = c16 ^ (row & 7);
            uint4 v = *reinterpret_cast<const uint4*>(T + (size_t)row*128 + c16*8);
            *reinterpret_cast<uint4*>(&Ws[row*128 + c16s*8]) = v;
        }
        __syncthreads();
        #pragma unroll
        for (int kk = 0; kk < 4; ++kk){
            const int k0 = kk*32;
            short8_t a[2];
            #pragma unroll
            for (int rf = 0; rf < 2; ++rf){
                size_t gr = (size_t)(r0 + wrow + rf*16 + l15);
                a[rf] = *reinterpret_cast<const short8_t*>(A + gr*128 + k0 + lg*8);
            }
            if (md){
                a[0] = norm_frag(a[0], ns, k0 + lg*8, md == 2);
                a[1] = norm_frag(a[1], ns, k0 + lg*8, md == 2);
            }
            #pragma unroll
            for (int cf = 0; cf < NCF; ++cf){
                int row  = cf*16 + l15;
                int c16  = (k0 >> 3) + lg;
                int c16s = c16 ^ (row & 7);
                short8_t b = *reinterpret_cast<const short8_t*>(&Ws[row*128 + c16s*8]);
                acc[0][cf] = __builtin_amdgcn_mfma_f32_16x16x32_bf16(a[0], b, acc[0][cf], 0, 0, 0);
                acc[1][cf] = __builtin_amdgcn_mfma_f32_16x16x32_bf16(a[1], b, acc[1][cf], 0, 0, 0);
            }
        }
    }

    float bs[NCF];
    #pragma unroll
    for (int cf = 0; cf < NCF; ++cf) bs[cf] = bias[cf*16 + l15];

    float s1[NCF], s2[NCF];
    #pragma unroll
    for (int cf = 0; cf < NCF; ++cf){ s1[cf] = 0.f; s2[cf] = 0.f; }

    __syncthreads();   // Ws B-staging done; reuse as C tile

    #pragma unroll
    for (int rf = 0; rf < 2; ++rf){
        #pragma unroll
        for (int q = 0; q < 4; ++q){
            int row_l = wrow + rf*16 + lg*4 + q;
            bool valid = (r0 + row_l) < N;
            #pragma unroll
            for (int cf = 0; cf < NCF; ++cf){
                float v = acc[rf][cf][q] + bs[cf];
                if (STATS && valid){ s1[cf] += v; s2[cf] += v*v; }
                if (OUTBF) Ws[row_l*140 + cf*16 + l15] = f2b(v);
                else       reinterpret_cast<float*>(Ws)[row_l*70 + cf*16 + l15] = v;
            }
        }
    }
    __syncthreads();

    const int tr = t >> 4, tc = t & 15;
    #pragma unroll
    for (int i = 0; i < 8; ++i){
        int row_l = i*16 + tr;
        int gr = r0 + row_l;
        if (gr < N){
            if (OUTBF){
                uint4 v = *reinterpret_cast<const uint4*>(&Ws[row_l*140 + tc*8]);
                *reinterpret_cast<uint4*>(&out_bf[(size_t)gr*(NCF*16) + tc*8]) = v;
            } else {
                float4 v = *reinterpret_cast<const float4*>(
                    &reinterpret_cast<float*>(Ws)[row_l*70 + tc*4]);
                *reinterpret_cast<float4*>(&out_f32[(size_t)gr*(NCF*16) + tc*4]) = v;
            }
        }
    }

    if (STATS){
        #pragma unroll
        for (int cf = 0; cf < NCF; ++cf){
            s1[cf] += __shfl_xor(s1[cf], 16);
            s1[cf] += __shfl_xor(s1[cf], 32);
            s2[cf] += __shfl_xor(s2[cf], 16);
            s2[cf] += __shfl_xor(s2[cf], 32);
        }
        if (l < 16){
            float* pb = partials + (size_t)(blockIdx.x*4 + w)*256;
            #pragma unroll
            for (int cf = 0; cf < NCF; ++cf){
                pb[cf*16 + l15]       = s1[cf];
                pb[128 + cf*16 + l15] = s2[cf];
            }
        }
    }
}

// ---------------------------------------------------------------- BN reduce (256 thr)
__global__ __launch_bounds__(256) void k_bnreduce(
    const float* __restrict__ partials, int I, int N,
    const float* __restrict__ gamma, const float* __restrict__ beta,
    float* __restrict__ ss)
{
    __shared__ float red[512];
    int c = blockIdx.x;
    int t = threadIdx.x;
    float s1 = 0.f, s2 = 0.f;
    for (int i = t; i < I; i += 256){
        s1 += partials[(size_t)i*256 + c];
        s2 += partials[(size_t)i*256 + 128 + c];
    }
    red[t] = s1; red[256+t] = s2;
    __syncthreads();
    for (int off = 128; off; off >>= 1){
        if (t < off){ red[t] += red[t+off]; red[256+t] += red[256+t+off]; }
        __syncthreads();
    }
    if (t == 0){
        float m   = red[0] / (float)N;
        float var = red[256] / (float)N - m*m;
        float sc  = rsqrtf(var + 1e-5f) * gamma[c];
        ss[c]     = sc;
        ss[128+c] = beta[c] - m*sc;
    }
}

// ---------------------------------------------------------------- launch
extern "C" void kernel_launch(void* const* d_in, const int* in_sizes, int n_in,
                              void* d_out, int out_size, void* d_ws, size_t ws_size,
                              hipStream_t stream)
{
    const float* x     = (const float*)d_in[0];
    const int*   ei    = (const int*)  d_in[1];
    const float* Wl    = (const float*)d_in[2];
    const float* bl    = (const float*)d_in[3];
    const float* Wr    = (const float*)d_in[4];
    const float* gamma = (const float*)d_in[5];
    const float* beta  = (const float*)d_in[6];
    const float* W1    = (const float*)d_in[7];
    const float* b1    = (const float*)d_in[8];
    const float* g1    = (const float*)d_in[9];
    const float* be1   = (const float*)d_in[10];
    const float* W2    = (const float*)d_in[11];
    const float* b2    = (const float*)d_in[12];
    float* out = (float*)d_out;

    const int N  = in_sizes[0] / 128;
    const int E  = in_sizes[1] / 2;
    const int NB = CDIV(N, 128);
    const size_t NPAD = (size_t)NB * 128;
    const int* src = ei;
    const int* dst = ei + E;

    const int NBUCK = CDIV(N, 256);

    char* w = (char*)d_ws;
    const size_t SB = NPAD * 128 * sizeof(ushort);
    ushort* x_bf = (ushort*)(w + 0*SB);
    ushort* pre0 = (ushort*)(w + 1*SB);
    ushort* pre1 = (ushort*)(w + 2*SB);
    ushort* pre2 = (ushort*)(w + 3*SB);
    ushort* aggb = (ushort*)(w + 4*SB);
    ushort* preh = (ushort*)(w + 5*SB);
    char* p = w + 6*SB;
    ushort* WtL = (ushort*)p;  p += (size_t)3*16384*2;
    ushort* WtR = (ushort*)p;  p += (size_t)3*16384*2;
    ushort* Wt1 = (ushort*)p;  p += (size_t)4*16384*2;
    ushort* Wt2 = (ushort*)p;  p += (size_t)8192*2;
    float* partials = (float*)p; p += (size_t)NB*4*256*sizeof(float);
    uint*  ebuf     = (uint*)p;  p += (size_t)E*4;
    int*   col_idx  = (int*)p;   p += (size_t)E*4;
    int*   row_ptr  = (int*)p;   p += (size_t)(N+1)*4;
    float* inv_deg  = (float*)p; p += (size_t)N*4;
    int*   bcnt     = (int*)p;   p += 512*4;
    int*   bbase    = (int*)p;   p += 516*4;
    int*   gcur     = (int*)p;   p += 512*4;
    float* ss0      = (float*)p; p += 256*4;
    float* ss1      = (float*)p; p += 256*4;
    float* ss2      = (float*)p; p += 256*4;
    float* ssh      = (float*)p; p += 256*4;

    // conversions
    const int n4 = N * 32;
    k_cvt_x<<<CDIV(n4,256), 256, 0, stream>>>(x, x_bf, n4);
    k_cvt_w<<<CDIV(10*16384+8192,256), 256, 0, stream>>>(Wl, Wr, W1, W2, WtL, WtR, Wt1, Wt2);

    // bucketed CSR build
    hipMemsetAsync(bcnt, 0, 512*4, stream);
    k_bcount<<<CDIV(E,4096), 256, 0, stream>>>(dst, E, NBUCK, bcnt);
    k_bscan<<<1, 512, 0, stream>>>(bcnt, NBUCK, E, bbase, gcur);
    k_bucketA<<<CDIV(E,4096), 256, 0, stream>>>(src, dst, E, NBUCK, gcur, ebuf);
    k_build<<<NBUCK, 256, 0, stream>>>(ebuf, bbase, N, E, row_ptr, inv_deg, col_idx);

    ushort* pre[3] = {pre0, pre1, pre2};
    float*  ssl[3] = {ss0, ss1, ss2};
    const int I = NB * 4;

    // ---- 3 SAGE layers (normalized h never materialized; norm at consumers)
    for (int L = 0; L < 3; ++L){
        if (L == 0)
            k_agg_bf<0><<<CDIV(N,4), 256, 0, stream>>>(x_bf, row_ptr, col_idx, inv_deg,
                                                       nullptr, aggb, N);
        else
            k_agg_bf<1><<<CDIV(N,4), 256, 0, stream>>>(pre[L-1], row_ptr, col_idx, inv_deg,
                                                       ssl[L-1], aggb, N);
        const ushort* hsrc = (L == 0) ? x_bf : pre[L-1];
        const float*  hns  = (L == 0) ? nullptr : ssl[L-1];
        int hmode = (L == 0) ? 0 : 1;
        k_gemm_mfma<8,1,1><<<NB, 256, 0, stream>>>(
            aggb, WtL + (size_t)L*16384,
            hsrc, WtR + (size_t)L*16384,
            nullptr, nullptr, nullptr, nullptr,
            nullptr, hns, nullptr, nullptr,
            0, hmode, 0, 0,
            2, bl + (size_t)L*128, pre[L], nullptr, partials, N);
        k_bnreduce<<<128, 256, 0, stream>>>(partials, I, N,
            gamma + (size_t)L*128, beta + (size_t)L*128, ssl[L]);
    }

    // ---- head: z = [x, h1, h2, h3] @ W1 + b1 (h applied from pre via ss)
    k_gemm_mfma<8,1,1><<<NB, 256, 0, stream>>>(
        x_bf, Wt1 + 0,
        pre0, Wt1 + 16384,
        pre1, Wt1 + 2*16384,
        pre2, Wt1 + 3*16384,
        nullptr, ss0, ss1, ss2,
        0, 1, 1, 1,
        4, b1, preh, nullptr, partials, N);
    k_bnreduce<<<128, 256, 0, stream>>>(partials, I, N, g1, be1, ssh);

    // ---- out: leaky(bn(preh)) @ W2 + b2 -> f32 d_out
    k_gemm_mfma<4,0,0><<<NB, 256, 0, stream>>>(
        preh, Wt2, nullptr, nullptr, nullptr, nullptr, nullptr, nullptr,
        ssh, nullptr, nullptr, nullptr,
        2, 0, 0, 0,
        1, b2, nullptr, out, partials, N);
}